// Round 12
// baseline (49.960 us; speedup 1.0000x reference)
//
#include <hip/hip_runtime.h>
#include <math.h>

#define DIM 1024
#define D4  (DIM / 4)      // 256 float4 per row
#define SNUM 5
#define EPSL 1e-6f
#define MARGINL 1.0f
#define NBUCKET 64
#define FIXSCALE 4294967296.0  // 2^32

__device__ __forceinline__ float sq4(const float4& x, const float4& y) {
    const float dx = x.x - y.x + EPSL;
    const float dy = x.y - y.y + EPSL;
    const float dz = x.z - y.z + EPSL;
    const float dw = x.w - y.w + EPSL;
    float s = dx * dx;
    s = fmaf(dy, dy, s);
    s = fmaf(dz, dz, s);
    s = fmaf(dw, dw, s);
    return s;
}

// Merged-butterfly primitive: one shfl_xor step reduces across bit m AND merges
// two accumulators (lanes with bit m unset end up owning x's sum, set -> y's).
__device__ __forceinline__ float merge_red(float x, float y, int m, int lane) {
    const float send = (lane & m) ? x : y;
    const float recv = __shfl_xor(send, m, 64);
    const float keep = (lane & m) ? y : x;
    return keep + recv;
}

// Reduce 12 accumulators across 64 lanes in 14 shuffles. Lane ends with the full
// sum of acc id = b2 ? 8+2*b4+b5 : 4*b3+2*b4+b5; rep lanes are canonical.
__device__ __forceinline__ float butterfly12(const float* acc, int lane) {
    const float r0 = merge_red(acc[0],  acc[1],  32, lane);
    const float r1 = merge_red(acc[2],  acc[3],  32, lane);
    const float r2 = merge_red(acc[4],  acc[5],  32, lane);
    const float r3 = merge_red(acc[6],  acc[7],  32, lane);
    const float r4 = merge_red(acc[8],  acc[9],  32, lane);
    const float r5 = merge_red(acc[10], acc[11], 32, lane);
    const float s0 = merge_red(r0, r1, 16, lane);
    const float s1 = merge_red(r2, r3, 16, lane);
    const float s2 = merge_red(r4, r5, 16, lane);
    const float t0 = merge_red(s0, s1, 8, lane);
    const float t1 = s2 + __shfl_xor(s2, 8, 64);
    float u = merge_red(t0, t1, 4, lane);
    u += __shfl_xor(u, 2, 64);
    u += __shfl_xor(u, 1, 64);
    return u;
}

// One block per anchor PAIR (R10/R11 structure, 17.3us). THIS ROUND'S DELTA:
// fused mean — per-block u64 fixed-point atomicAdd into 64 spread buckets
// (relaxed, LLC-executed) + RELEASE-ordered done-counter (no __threadfence:
// R5's 97us was the per-wave cache-maintenance fence, not atomic throughput;
// R3/R4 proved this bucket+ctr+RMW-read pattern is exact). Kills the second
// dispatch node and the inter-kernel L2 flush boundary (~10us of structural
// tail identified by R9-R11's three nulls on the hinge body).
__global__ __launch_bounds__(256) void hinge_kernel(const float* __restrict__ vfeat,
                                                    const float* __restrict__ afeat,
                                                    unsigned long long* __restrict__ bucket,
                                                    unsigned int* __restrict__ done_ctr,
                                                    float* __restrict__ out,
                                                    int B, int nblocks) {
    // XCD-chunked bijective swizzle (R2: -46%): contiguous anchors per XCD.
    int b = blockIdx.x;
    if ((nblocks & 7) == 0) {
        const int chunk = nblocks >> 3;
        b = (b & 7) * chunk + (b >> 3);
    }
    const int k0 = 2 * b;
    const int k1 = k0 + 1;
    const int t = threadIdx.x;
    const int wave = t >> 6;
    const int lane = t & 63;

    const float4* __restrict__ v4 = reinterpret_cast<const float4*>(vfeat);
    const float4* __restrict__ a4 = reinterpret_cast<const float4*>(afeat);

    // acc0: anchor k0 ([0]=pos, [1..5]=n1, [6..10]=n2, [11]=pad); acc1: anchor k1
    float acc0[12], acc1[12];
    acc0[11] = 0.0f; acc1[11] = 0.0f;

    const float4 vk0 = v4[(size_t)k0 * D4 + t];
    const float4 ak0 = a4[(size_t)k0 * D4 + t];
    const float4 vk1 = v4[(size_t)k1 * D4 + t];
    const float4 ak1 = a4[(size_t)k1 * D4 + t];

    if (k0 >= SNUM) {
        // load cluster: rows k0+2..k0+6, both matrices, into registers
        float4 ar[5], vr[5];
        #pragma unroll
        for (int r = 0; r < 5; ++r) {
            int row = k0 + 2 + r;
            if (row >= B) row -= B;
            ar[r] = a4[(size_t)row * D4 + t];
            vr[r] = v4[(size_t)row * D4 + t];
        }
        __builtin_amdgcn_sched_barrier(0);

        acc0[0] = sq4(vk0, ak0);
        acc1[0] = sq4(vk1, ak1);
        acc0[1] = sq4(vk0, ak1);        // k0's m=0 negative row is k1
        acc0[6] = sq4(ak0, vk1);
        #pragma unroll
        for (int r = 0; r < 4; ++r) {   // k0: rows k0+2..k0+5 (m=1..4)
            acc0[2 + r] = sq4(vk0, ar[r]);
            acc0[7 + r] = sq4(ak0, vr[r]);
        }
        #pragma unroll
        for (int r = 0; r < 5; ++r) {   // k1: rows k0+2..k0+6 (m=0..4)
            acc1[1 + r] = sq4(vk1, ar[r]);
            acc1[6 + r] = sq4(ak1, vr[r]);
        }
    } else {
        // generic path (k0 < SNUM: reference's m==k duplicate) — 3 blocks only.
        acc0[0] = sq4(vk0, ak0);
        acc1[0] = sq4(vk1, ak1);
        #pragma unroll
        for (int m = 0; m < SNUM; ++m) {
            int t0 = k0 + m + 1; if (m == k0) t0 = k0 + 1; if (t0 >= B) t0 -= B;
            int t1 = k1 + m + 1; if (m == k1) t1 = k1 + 1; if (t1 >= B) t1 -= B;
            const float4 a0 = a4[(size_t)t0 * D4 + t];
            const float4 v0 = v4[(size_t)t0 * D4 + t];
            const float4 a1 = a4[(size_t)t1 * D4 + t];
            const float4 v1 = v4[(size_t)t1 * D4 + t];
            acc0[1 + m] = sq4(vk0, a0);
            acc0[6 + m] = sq4(ak0, v0);
            acc1[1 + m] = sq4(vk1, a1);
            acc1[6 + m] = sq4(ak1, v1);
        }
    }

    const float u0 = butterfly12(acc0, lane);
    const float u1 = butterfly12(acc1, lane);

    // lane -> acc id, one canonical representative lane per id
    const int b5 = (lane >> 5) & 1, b4 = (lane >> 4) & 1;
    const int b3 = (lane >> 3) & 1, b2 = (lane >> 2) & 1;
    const int id = b2 ? (8 + 2 * b4 + b5) : (4 * b3 + 2 * b4 + b5);
    const bool rep = ((lane & 3) == 0) && (!b2 || !b3);

    __shared__ float sh[4][24];
    __shared__ int sh_last;
    if (rep) {
        sh[wave][id]      = u0;
        sh[wave][12 + id] = u1;
    }
    __syncthreads();

    if (t == 0) {
        float tot[22];
        #pragma unroll
        for (int i = 0; i < 11; ++i) {
            tot[i]      = sh[0][i] + sh[1][i] + sh[2][i] + sh[3][i];
            tot[11 + i] = sh[0][12 + i] + sh[1][12 + i] + sh[2][12 + i] + sh[3][12 + i];
        }
        const float dp0 = sqrtf(tot[0]);
        float dn1_0 = sqrtf(tot[1]), dn2_0 = sqrtf(tot[6]);
        const float dp1 = sqrtf(tot[11]);
        float dn1_1 = sqrtf(tot[12]), dn2_1 = sqrtf(tot[17]);
        #pragma unroll
        for (int m = 1; m < SNUM; ++m) {
            dn1_0 = fminf(dn1_0, sqrtf(tot[1 + m]));
            dn2_0 = fminf(dn2_0, sqrtf(tot[6 + m]));
            dn1_1 = fminf(dn1_1, sqrtf(tot[12 + m]));
            dn2_1 = fminf(dn2_1, sqrtf(tot[17 + m]));
        }
        const float h0 = fmaxf(MARGINL + 2.0f * dp0 - dn1_0 - dn2_0, 0.0f);
        const float h1 = fmaxf(MARGINL + 2.0f * dp1 - dn1_1 - dn2_1, 0.0f);

        // deterministic fixed-point accumulate into 64 spread buckets (relaxed
        // RMW, executes at LLC — value travels with the op, no ordering needed)
        const unsigned long long fx =
            (unsigned long long)((double)(h0 + h1) * FIXSCALE + 0.5);
        atomicAdd(&bucket[blockIdx.x & (NBUCKET - 1)], fx);

        // release-ordered counter: waits vmcnt(0) (bucket RMW at LLC) before the
        // RMW issues; acquire side synchronizes the last block. NO threadfence.
        const unsigned int old = __hip_atomic_fetch_add(
            done_ctr, 1u, __ATOMIC_ACQ_REL, __HIP_MEMORY_SCOPE_AGENT);
        sh_last = (old == (unsigned int)(nblocks - 1)) ? 1 : 0;
    }
    __syncthreads();

    // last block: wave 0 reads all 64 buckets via RMW (LLC-coherent), 64-bit
    // butterfly, lane 0 writes the mean.
    if (sh_last && wave == 0) {
        unsigned long long v = atomicAdd(&bucket[lane], 0ull);
        #pragma unroll
        for (int off = 32; off > 0; off >>= 1)
            v += __shfl_xor(v, off, 64);
        if (lane == 0)
            out[0] = (float)(((double)v / FIXSCALE) / (double)B);
    }
}

extern "C" void kernel_launch(void* const* d_in, const int* in_sizes, int n_in,
                              void* d_out, int out_size, void* d_ws, size_t ws_size,
                              hipStream_t stream) {
    const float* vfeat = (const float*)d_in[0];
    const float* afeat = (const float*)d_in[1];
    const int B = in_sizes[0] / DIM;
    const int nblocks = B / 2;

    unsigned long long* bucket = (unsigned long long*)d_ws;          // 64 * 8 B
    unsigned int* done_ctr = (unsigned int*)((char*)d_ws + NBUCKET * 8);
    float* out = (float*)d_out;

    // zero buckets + counter each call (graph-capturable memset node)
    hipMemsetAsync(d_ws, 0, NBUCKET * 8 + 16, stream);

    hinge_kernel<<<nblocks, 256, 0, stream>>>(vfeat, afeat, bucket, done_ctr, out,
                                              B, nblocks);
}

// Round 13
// 48.648 us; speedup vs baseline: 1.0270x; 1.0270x over previous
//
#include <hip/hip_runtime.h>
#include <math.h>

#define DIM 1024
#define D4  (DIM / 4)      // 256 float4 per row
#define SNUM 5
#define EPSL 1e-6f
#define MARGINL 1.0f
#define NBUCKET 64
#define FIXSCALE 4294967296.0  // 2^32

__device__ __forceinline__ float sq4(const float4& x, const float4& y) {
    const float dx = x.x - y.x + EPSL;
    const float dy = x.y - y.y + EPSL;
    const float dz = x.z - y.z + EPSL;
    const float dw = x.w - y.w + EPSL;
    float s = dx * dx;
    s = fmaf(dy, dy, s);
    s = fmaf(dz, dz, s);
    s = fmaf(dw, dw, s);
    return s;
}

// Merged-butterfly primitive: one shfl_xor step reduces across bit m AND merges
// two accumulators (lanes with bit m unset end up owning x's sum, set -> y's).
__device__ __forceinline__ float merge_red(float x, float y, int m, int lane) {
    const float send = (lane & m) ? x : y;
    const float recv = __shfl_xor(send, m, 64);
    const float keep = (lane & m) ? y : x;
    return keep + recv;
}

// Reduce 12 accumulators across 64 lanes in 14 shuffles. Lane ends with the full
// sum of acc id = b2 ? 8+2*b4+b5 : 4*b3+2*b4+b5; rep lanes are canonical.
__device__ __forceinline__ float butterfly12(const float* acc, int lane) {
    const float r0 = merge_red(acc[0],  acc[1],  32, lane);
    const float r1 = merge_red(acc[2],  acc[3],  32, lane);
    const float r2 = merge_red(acc[4],  acc[5],  32, lane);
    const float r3 = merge_red(acc[6],  acc[7],  32, lane);
    const float r4 = merge_red(acc[8],  acc[9],  32, lane);
    const float r5 = merge_red(acc[10], acc[11], 32, lane);
    const float s0 = merge_red(r0, r1, 16, lane);
    const float s1 = merge_red(r2, r3, 16, lane);
    const float s2 = merge_red(r4, r5, 16, lane);
    const float t0 = merge_red(s0, s1, 8, lane);
    const float t1 = s2 + __shfl_xor(s2, 8, 64);
    float u = merge_red(t0, t1, 4, lane);
    u += __shfl_xor(u, 2, 64);
    u += __shfl_xor(u, 1, 64);
    return u;
}

// R11 body (17.3us, proven) + fused mean with a tail engineered around the
// measured ~17ns/line device-atomic serialization constant (R12: 2048 RMWs on
// ONE ctr line = +40us):
//   - fixed-point buckets PADDED to 64B (64 lines, 32 RMWs each in parallel)
//   - hierarchical done-counters: 64 padded group ctrs (32 release-RMWs each,
//     parallel) -> one master ctr (only 64 serialized RMWs)
//   - ordering via __hip_atomic_fetch_add(ACQ_REL, AGENT) (R12 proved exact,
//     absmax 0.0); NO threadfence.
// Kills the mean dispatch + inter-kernel boundary (~4-6us of R11's 17.3).
__global__ __launch_bounds__(256) void hinge_kernel(const float* __restrict__ vfeat,
                                                    const float* __restrict__ afeat,
                                                    unsigned long long* __restrict__ bucket,  // stride 8 ull = 64B
                                                    unsigned int* __restrict__ gctr,          // stride 16 u32 = 64B
                                                    unsigned int* __restrict__ master,
                                                    float* __restrict__ out,
                                                    int B, int nblocks) {
    // XCD-chunked bijective swizzle (R2: -46%): contiguous anchors per XCD.
    int b = blockIdx.x;
    if ((nblocks & 7) == 0) {
        const int chunk = nblocks >> 3;
        b = (b & 7) * chunk + (b >> 3);
    }
    const int k0 = 2 * b;
    const int k1 = k0 + 1;
    const int t = threadIdx.x;
    const int wave = t >> 6;
    const int lane = t & 63;

    const float4* __restrict__ v4 = reinterpret_cast<const float4*>(vfeat);
    const float4* __restrict__ a4 = reinterpret_cast<const float4*>(afeat);

    // acc0: anchor k0 ([0]=pos, [1..5]=n1, [6..10]=n2, [11]=pad); acc1: anchor k1
    float acc0[12], acc1[12];
    acc0[11] = 0.0f; acc1[11] = 0.0f;

    const float4 vk0 = v4[(size_t)k0 * D4 + t];
    const float4 ak0 = a4[(size_t)k0 * D4 + t];
    const float4 vk1 = v4[(size_t)k1 * D4 + t];
    const float4 ak1 = a4[(size_t)k1 * D4 + t];

    if (k0 >= SNUM) {
        // load cluster: rows k0+2..k0+6, both matrices, into registers
        float4 ar[5], vr[5];
        #pragma unroll
        for (int r = 0; r < 5; ++r) {
            int row = k0 + 2 + r;
            if (row >= B) row -= B;
            ar[r] = a4[(size_t)row * D4 + t];
            vr[r] = v4[(size_t)row * D4 + t];
        }
        __builtin_amdgcn_sched_barrier(0);

        acc0[0] = sq4(vk0, ak0);
        acc1[0] = sq4(vk1, ak1);
        acc0[1] = sq4(vk0, ak1);        // k0's m=0 negative row is k1
        acc0[6] = sq4(ak0, vk1);
        #pragma unroll
        for (int r = 0; r < 4; ++r) {   // k0: rows k0+2..k0+5 (m=1..4)
            acc0[2 + r] = sq4(vk0, ar[r]);
            acc0[7 + r] = sq4(ak0, vr[r]);
        }
        #pragma unroll
        for (int r = 0; r < 5; ++r) {   // k1: rows k0+2..k0+6 (m=0..4)
            acc1[1 + r] = sq4(vk1, ar[r]);
            acc1[6 + r] = sq4(ak1, vr[r]);
        }
    } else {
        // generic path (k0 < SNUM: reference's m==k duplicate) — 3 blocks only.
        acc0[0] = sq4(vk0, ak0);
        acc1[0] = sq4(vk1, ak1);
        #pragma unroll
        for (int m = 0; m < SNUM; ++m) {
            int t0 = k0 + m + 1; if (m == k0) t0 = k0 + 1; if (t0 >= B) t0 -= B;
            int t1 = k1 + m + 1; if (m == k1) t1 = k1 + 1; if (t1 >= B) t1 -= B;
            const float4 a0 = a4[(size_t)t0 * D4 + t];
            const float4 v0 = v4[(size_t)t0 * D4 + t];
            const float4 a1 = a4[(size_t)t1 * D4 + t];
            const float4 v1 = v4[(size_t)t1 * D4 + t];
            acc0[1 + m] = sq4(vk0, a0);
            acc0[6 + m] = sq4(ak0, v0);
            acc1[1 + m] = sq4(vk1, a1);
            acc1[6 + m] = sq4(ak1, v1);
        }
    }

    const float u0 = butterfly12(acc0, lane);
    const float u1 = butterfly12(acc1, lane);

    // lane -> acc id, one canonical representative lane per id
    const int b5 = (lane >> 5) & 1, b4 = (lane >> 4) & 1;
    const int b3 = (lane >> 3) & 1, b2 = (lane >> 2) & 1;
    const int id = b2 ? (8 + 2 * b4 + b5) : (4 * b3 + 2 * b4 + b5);
    const bool rep = ((lane & 3) == 0) && (!b2 || !b3);

    __shared__ float sh[4][24];
    __shared__ int sh_last;
    if (rep) {
        sh[wave][id]      = u0;
        sh[wave][12 + id] = u1;
    }
    __syncthreads();

    if (t == 0) {
        float tot[22];
        #pragma unroll
        for (int i = 0; i < 11; ++i) {
            tot[i]      = sh[0][i] + sh[1][i] + sh[2][i] + sh[3][i];
            tot[11 + i] = sh[0][12 + i] + sh[1][12 + i] + sh[2][12 + i] + sh[3][12 + i];
        }
        const float dp0 = sqrtf(tot[0]);
        float dn1_0 = sqrtf(tot[1]), dn2_0 = sqrtf(tot[6]);
        const float dp1 = sqrtf(tot[11]);
        float dn1_1 = sqrtf(tot[12]), dn2_1 = sqrtf(tot[17]);
        #pragma unroll
        for (int m = 1; m < SNUM; ++m) {
            dn1_0 = fminf(dn1_0, sqrtf(tot[1 + m]));
            dn2_0 = fminf(dn2_0, sqrtf(tot[6 + m]));
            dn1_1 = fminf(dn1_1, sqrtf(tot[12 + m]));
            dn2_1 = fminf(dn2_1, sqrtf(tot[17 + m]));
        }
        const float h0 = fmaxf(MARGINL + 2.0f * dp0 - dn1_0 - dn2_0, 0.0f);
        const float h1 = fmaxf(MARGINL + 2.0f * dp1 - dn1_1 - dn2_1, 0.0f);

        // deterministic fixed-point accumulate, 64 buckets padded to 64B lines
        const int g = blockIdx.x & (NBUCKET - 1);
        const unsigned long long fx =
            (unsigned long long)((double)(h0 + h1) * FIXSCALE + 0.5);
        atomicAdd(&bucket[g * 8], fx);

        // group counter (padded line, release: waits bucket RMW to LLC first)
        const unsigned int gsz = (unsigned int)((nblocks >> 6) +
                                 ((g < (nblocks & (NBUCKET - 1))) ? 1 : 0));
        const unsigned int gold = __hip_atomic_fetch_add(
            &gctr[g * 16], 1u, __ATOMIC_ACQ_REL, __HIP_MEMORY_SCOPE_AGENT);
        int last = 0;
        if (gold == gsz - 1) {
            // group-last: tick the master (only 64 serialized RMWs total)
            const unsigned int mold = __hip_atomic_fetch_add(
                master, 1u, __ATOMIC_ACQ_REL, __HIP_MEMORY_SCOPE_AGENT);
            last = (mold == (unsigned int)(NBUCKET - 1)) ? 1 : 0;
        }
        sh_last = last;
    }
    __syncthreads();

    // global-last block: wave 0 reads all 64 padded buckets via RMW
    // (LLC-coherent), 64-bit butterfly, lane 0 writes the mean.
    if (sh_last && wave == 0) {
        unsigned long long v = atomicAdd(&bucket[lane * 8], 0ull);
        #pragma unroll
        for (int off = 32; off > 0; off >>= 1)
            v += __shfl_xor(v, off, 64);
        if (lane == 0)
            out[0] = (float)(((double)v / FIXSCALE) / (double)B);
    }
}

extern "C" void kernel_launch(void* const* d_in, const int* in_sizes, int n_in,
                              void* d_out, int out_size, void* d_ws, size_t ws_size,
                              hipStream_t stream) {
    const float* vfeat = (const float*)d_in[0];
    const float* afeat = (const float*)d_in[1];
    const int B = in_sizes[0] / DIM;
    const int nblocks = B / 2;

    // ws layout (all 64B-padded): [0,4K) buckets, [4K,8K) group ctrs, [8K] master
    unsigned long long* bucket = (unsigned long long*)d_ws;
    unsigned int* gctr   = (unsigned int*)((char*)d_ws + 4096);
    unsigned int* master = (unsigned int*)((char*)d_ws + 8192);
    float* out = (float*)d_out;

    // zero buckets + counters each call (graph-capturable memset node)
    hipMemsetAsync(d_ws, 0, 8192 + 64, stream);

    hinge_kernel<<<nblocks, 256, 0, stream>>>(vfeat, afeat, bucket, gctr, master,
                                              out, B, nblocks);
}

// Round 14
// 21.449 us; speedup vs baseline: 2.3292x; 2.2681x over previous
//
#include <hip/hip_runtime.h>
#include <math.h>

#define DIM 1024
#define D4  (DIM / 4)      // 256 float4 per row
#define SNUM 5
#define EPSL 1e-6f
#define MARGINL 1.0f
#define NBUCKET 64
#define FIXSCALE 4294967296.0  // 2^32

__device__ __forceinline__ float sq4(const float4& x, const float4& y) {
    const float dx = x.x - y.x + EPSL;
    const float dy = x.y - y.y + EPSL;
    const float dz = x.z - y.z + EPSL;
    const float dw = x.w - y.w + EPSL;
    float s = dx * dx;
    s = fmaf(dy, dy, s);
    s = fmaf(dz, dz, s);
    s = fmaf(dw, dw, s);
    return s;
}

__device__ __forceinline__ unsigned long long rmw_add_u64(unsigned long long* p,
                                                          unsigned long long v) {
    return __hip_atomic_fetch_add(p, v, __ATOMIC_RELAXED, __HIP_MEMORY_SCOPE_AGENT);
}
__device__ __forceinline__ unsigned int rmw_add_u32(unsigned int* p, unsigned int v) {
    return __hip_atomic_fetch_add(p, v, __ATOMIC_RELAXED, __HIP_MEMORY_SCOPE_AGENT);
}

// Merged-butterfly primitive: one shfl_xor step reduces across bit m AND merges
// two accumulators (lanes with bit m unset end up owning x's sum, set -> y's).
__device__ __forceinline__ float merge_red(float x, float y, int m, int lane) {
    const float send = (lane & m) ? x : y;
    const float recv = __shfl_xor(send, m, 64);
    const float keep = (lane & m) ? y : x;
    return keep + recv;
}

// Reduce 12 accumulators across 64 lanes in 14 shuffles. Lane ends with the full
// sum of acc id = b2 ? 8+2*b4+b5 : 4*b3+2*b4+b5; rep lanes are canonical.
__device__ __forceinline__ float butterfly12(const float* acc, int lane) {
    const float r0 = merge_red(acc[0],  acc[1],  32, lane);
    const float r1 = merge_red(acc[2],  acc[3],  32, lane);
    const float r2 = merge_red(acc[4],  acc[5],  32, lane);
    const float r3 = merge_red(acc[6],  acc[7],  32, lane);
    const float r4 = merge_red(acc[8],  acc[9],  32, lane);
    const float r5 = merge_red(acc[10], acc[11], 32, lane);
    const float s0 = merge_red(r0, r1, 16, lane);
    const float s1 = merge_red(r2, r3, 16, lane);
    const float s2 = merge_red(r4, r5, 16, lane);
    const float t0 = merge_red(s0, s1, 8, lane);
    const float t1 = s2 + __shfl_xor(s2, 8, 64);
    float u = merge_red(t0, t1, 4, lane);
    u += __shfl_xor(u, 2, 64);
    u += __shfl_xor(u, 1, 64);
    return u;
}

// R11 body (proven) + fused mean with a ZERO-ORDERED-OP tail.
// Model from R5/R12/R13: every device-scope ORDERED op (threadfence, ACQ_REL
// atomic) costs ~20ns on a globally serialized cache-maintenance resource
// (4096x fence=+87us, 2048x acqrel=+49us, hierarchical acqrel=+41us — line
// spreading didn't help => not RMW contention). RELAXED RMWs execute at the
// LLC banks in parallel. Ordering chain here is pure RMW-at-LLC + vmcnt(0)
// waits (ack round-trip, overlapped across blocks, no maintenance):
//   bucket add -> vmcnt -> group ctr -> vmcnt -> master (64 RMWs total)
// master==63 => all gctr at LLC => all buckets at LLC => last block's
// atomicAdd(+0) reads are exact. Integer adds commute => deterministic.
__global__ __launch_bounds__(256) void hinge_kernel(const float* __restrict__ vfeat,
                                                    const float* __restrict__ afeat,
                                                    unsigned long long* __restrict__ bucket,  // stride 8 ull = 64B
                                                    unsigned int* __restrict__ gctr,          // stride 16 u32 = 64B
                                                    unsigned int* __restrict__ master,
                                                    float* __restrict__ out,
                                                    int B, int nblocks) {
    // XCD-chunked bijective swizzle (R2: -46%): contiguous anchors per XCD.
    int b = blockIdx.x;
    if ((nblocks & 7) == 0) {
        const int chunk = nblocks >> 3;
        b = (b & 7) * chunk + (b >> 3);
    }
    const int k0 = 2 * b;
    const int k1 = k0 + 1;
    const int t = threadIdx.x;
    const int wave = t >> 6;
    const int lane = t & 63;

    const float4* __restrict__ v4 = reinterpret_cast<const float4*>(vfeat);
    const float4* __restrict__ a4 = reinterpret_cast<const float4*>(afeat);

    // acc0: anchor k0 ([0]=pos, [1..5]=n1, [6..10]=n2, [11]=pad); acc1: anchor k1
    float acc0[12], acc1[12];
    acc0[11] = 0.0f; acc1[11] = 0.0f;

    const float4 vk0 = v4[(size_t)k0 * D4 + t];
    const float4 ak0 = a4[(size_t)k0 * D4 + t];
    const float4 vk1 = v4[(size_t)k1 * D4 + t];
    const float4 ak1 = a4[(size_t)k1 * D4 + t];

    if (k0 >= SNUM) {
        // load cluster: rows k0+2..k0+6, both matrices, into registers
        float4 ar[5], vr[5];
        #pragma unroll
        for (int r = 0; r < 5; ++r) {
            int row = k0 + 2 + r;
            if (row >= B) row -= B;
            ar[r] = a4[(size_t)row * D4 + t];
            vr[r] = v4[(size_t)row * D4 + t];
        }
        __builtin_amdgcn_sched_barrier(0);

        acc0[0] = sq4(vk0, ak0);
        acc1[0] = sq4(vk1, ak1);
        acc0[1] = sq4(vk0, ak1);        // k0's m=0 negative row is k1
        acc0[6] = sq4(ak0, vk1);
        #pragma unroll
        for (int r = 0; r < 4; ++r) {   // k0: rows k0+2..k0+5 (m=1..4)
            acc0[2 + r] = sq4(vk0, ar[r]);
            acc0[7 + r] = sq4(ak0, vr[r]);
        }
        #pragma unroll
        for (int r = 0; r < 5; ++r) {   // k1: rows k0+2..k0+6 (m=0..4)
            acc1[1 + r] = sq4(vk1, ar[r]);
            acc1[6 + r] = sq4(ak1, vr[r]);
        }
    } else {
        // generic path (k0 < SNUM: reference's m==k duplicate) — 3 blocks only.
        acc0[0] = sq4(vk0, ak0);
        acc1[0] = sq4(vk1, ak1);
        #pragma unroll
        for (int m = 0; m < SNUM; ++m) {
            int t0 = k0 + m + 1; if (m == k0) t0 = k0 + 1; if (t0 >= B) t0 -= B;
            int t1 = k1 + m + 1; if (m == k1) t1 = k1 + 1; if (t1 >= B) t1 -= B;
            const float4 a0 = a4[(size_t)t0 * D4 + t];
            const float4 v0 = v4[(size_t)t0 * D4 + t];
            const float4 a1 = a4[(size_t)t1 * D4 + t];
            const float4 v1 = v4[(size_t)t1 * D4 + t];
            acc0[1 + m] = sq4(vk0, a0);
            acc0[6 + m] = sq4(ak0, v0);
            acc1[1 + m] = sq4(vk1, a1);
            acc1[6 + m] = sq4(ak1, v1);
        }
    }

    const float u0 = butterfly12(acc0, lane);
    const float u1 = butterfly12(acc1, lane);

    // lane -> acc id, one canonical representative lane per id
    const int b5 = (lane >> 5) & 1, b4 = (lane >> 4) & 1;
    const int b3 = (lane >> 3) & 1, b2 = (lane >> 2) & 1;
    const int id = b2 ? (8 + 2 * b4 + b5) : (4 * b3 + 2 * b4 + b5);
    const bool rep = ((lane & 3) == 0) && (!b2 || !b3);

    __shared__ float sh[4][24];
    __shared__ int sh_last;
    if (rep) {
        sh[wave][id]      = u0;
        sh[wave][12 + id] = u1;
    }
    __syncthreads();

    if (t == 0) {
        float tot[22];
        #pragma unroll
        for (int i = 0; i < 11; ++i) {
            tot[i]      = sh[0][i] + sh[1][i] + sh[2][i] + sh[3][i];
            tot[11 + i] = sh[0][12 + i] + sh[1][12 + i] + sh[2][12 + i] + sh[3][12 + i];
        }
        const float dp0 = sqrtf(tot[0]);
        float dn1_0 = sqrtf(tot[1]), dn2_0 = sqrtf(tot[6]);
        const float dp1 = sqrtf(tot[11]);
        float dn1_1 = sqrtf(tot[12]), dn2_1 = sqrtf(tot[17]);
        #pragma unroll
        for (int m = 1; m < SNUM; ++m) {
            dn1_0 = fminf(dn1_0, sqrtf(tot[1 + m]));
            dn2_0 = fminf(dn2_0, sqrtf(tot[6 + m]));
            dn1_1 = fminf(dn1_1, sqrtf(tot[12 + m]));
            dn2_1 = fminf(dn2_1, sqrtf(tot[17 + m]));
        }
        const float h0 = fmaxf(MARGINL + 2.0f * dp0 - dn1_0 - dn2_0, 0.0f);
        const float h1 = fmaxf(MARGINL + 2.0f * dp1 - dn1_1 - dn2_1, 0.0f);

        // (1) bucket add — relaxed RMW, 64 padded lines, 32-way parallel
        const int g = blockIdx.x & (NBUCKET - 1);
        const unsigned long long fx =
            (unsigned long long)((double)(h0 + h1) * FIXSCALE + 0.5);
        const unsigned long long bold = rmw_add_u64(&bucket[g * 8], fx);
        asm volatile("" :: "v"((unsigned int)bold));          // keep the return
        asm volatile("s_waitcnt vmcnt(0)" ::: "memory");      // bucket at LLC

        // (2) group counter — relaxed RMW, padded line
        const unsigned int gsz = (unsigned int)((nblocks >> 6) +
                                 ((g < (nblocks & (NBUCKET - 1))) ? 1 : 0));
        const unsigned int gold = rmw_add_u32(&gctr[g * 16], 1u);
        int last = 0;
        if (gold == gsz - 1) {
            asm volatile("s_waitcnt vmcnt(0)" ::: "memory");  // gctr at LLC
            // (3) master — only 64 RMWs total
            const unsigned int mold = rmw_add_u32(master, 1u);
            last = (mold == (unsigned int)(NBUCKET - 1)) ? 1 : 0;
        }
        sh_last = last;
    }
    __syncthreads();

    // global-last block: wave 0 reads all 64 padded buckets via RMW-at-LLC,
    // 64-bit butterfly, lane 0 writes the mean.
    if (sh_last && wave == 0) {
        unsigned long long v = rmw_add_u64(&bucket[lane * 8], 0ull);
        #pragma unroll
        for (int off = 32; off > 0; off >>= 1)
            v += __shfl_xor(v, off, 64);
        if (lane == 0)
            out[0] = (float)(((double)v / FIXSCALE) / (double)B);
    }
}

extern "C" void kernel_launch(void* const* d_in, const int* in_sizes, int n_in,
                              void* d_out, int out_size, void* d_ws, size_t ws_size,
                              hipStream_t stream) {
    const float* vfeat = (const float*)d_in[0];
    const float* afeat = (const float*)d_in[1];
    const int B = in_sizes[0] / DIM;
    const int nblocks = B / 2;

    // ws layout (all 64B-padded): [0,4K) buckets, [4K,8K) group ctrs, [8K] master
    unsigned long long* bucket = (unsigned long long*)d_ws;
    unsigned int* gctr   = (unsigned int*)((char*)d_ws + 4096);
    unsigned int* master = (unsigned int*)((char*)d_ws + 8192);
    float* out = (float*)d_out;

    // zero buckets + counters each call (graph-capturable memset node)
    hipMemsetAsync(d_ws, 0, 8192 + 64, stream);

    hinge_kernel<<<nblocks, 256, 0, stream>>>(vfeat, afeat, bucket, gctr, master,
                                              out, B, nblocks);
}

// Round 15
// 17.134 us; speedup vs baseline: 2.9158x; 1.2519x over previous
//
#include <hip/hip_runtime.h>
#include <math.h>

#define DIM 1024
#define D4  (DIM / 4)      // 256 float4 per row
#define SNUM 5
#define EPSL 1e-6f
#define MARGINL 1.0f

__device__ __forceinline__ float sq4(const float4& x, const float4& y) {
    const float dx = x.x - y.x + EPSL;
    const float dy = x.y - y.y + EPSL;
    const float dz = x.z - y.z + EPSL;
    const float dw = x.w - y.w + EPSL;
    float s = dx * dx;
    s = fmaf(dy, dy, s);
    s = fmaf(dz, dz, s);
    s = fmaf(dw, dw, s);
    return s;
}

// Merged-butterfly primitive: one shfl_xor step reduces across bit m AND merges
// two accumulators (lanes with bit m unset end up owning x's sum, set -> y's).
__device__ __forceinline__ float merge_red(float x, float y, int m, int lane) {
    const float send = (lane & m) ? x : y;
    const float recv = __shfl_xor(send, m, 64);
    const float keep = (lane & m) ? y : x;
    return keep + recv;
}

// Reduce 12 accumulators across 64 lanes in 14 shuffles. Lane ends with the full
// sum of acc id = b2 ? 8+2*b4+b5 : 4*b3+2*b4+b5; rep lanes are canonical.
__device__ __forceinline__ float butterfly12(const float* acc, int lane) {
    const float r0 = merge_red(acc[0],  acc[1],  32, lane);
    const float r1 = merge_red(acc[2],  acc[3],  32, lane);
    const float r2 = merge_red(acc[4],  acc[5],  32, lane);
    const float r3 = merge_red(acc[6],  acc[7],  32, lane);
    const float r4 = merge_red(acc[8],  acc[9],  32, lane);
    const float r5 = merge_red(acc[10], acc[11], 32, lane);
    const float s0 = merge_red(r0, r1, 16, lane);
    const float s1 = merge_red(r2, r3, 16, lane);
    const float s2 = merge_red(r4, r5, 16, lane);
    const float t0 = merge_red(s0, s1, 8, lane);
    const float t1 = s2 + __shfl_xor(s2, 8, 64);
    float u = merge_red(t0, t1, 4, lane);
    u += __shfl_xor(u, 2, 64);
    u += __shfl_xor(u, 1, 64);
    return u;
}

// FINAL (R11 configuration, 17.3us proven):
//  - one block per anchor PAIR: 14 row-loads/pair instead of 24 (k1's own rows
//    are k0's first negatives; rows k0+2..k0+5 feed both anchors)
//  - XCD-chunked bijective blockIdx swizzle (R2: -46%; neighbor rows served
//    from the local XCD's L2)
//  - merged butterfly: 14 shuffles per 12 accumulators (R8: -7us; the DS pipe
//    was the binding resource at 66 shuffles/acc-set)
//  - plain two-kernel tail: R14 falsified the "expensive node boundary" theory
//    (fused tail with the cheapest possible sync = +4us vs this); every ordered
//    device-scope op costs ~20ns serialized (R5/R12/R13), so no atomics at all.
__global__ __launch_bounds__(256) void hinge_kernel(const float* __restrict__ vfeat,
                                                    const float* __restrict__ afeat,
                                                    float* __restrict__ bsum,
                                                    int B, int nblocks) {
    int b = blockIdx.x;
    if ((nblocks & 7) == 0) {
        const int chunk = nblocks >> 3;
        b = (b & 7) * chunk + (b >> 3);
    }
    const int k0 = 2 * b;
    const int k1 = k0 + 1;
    const int t = threadIdx.x;
    const int wave = t >> 6;
    const int lane = t & 63;

    const float4* __restrict__ v4 = reinterpret_cast<const float4*>(vfeat);
    const float4* __restrict__ a4 = reinterpret_cast<const float4*>(afeat);

    // acc0: anchor k0 ([0]=pos, [1..5]=n1, [6..10]=n2, [11]=pad); acc1: anchor k1
    float acc0[12], acc1[12];
    acc0[11] = 0.0f; acc1[11] = 0.0f;

    const float4 vk0 = v4[(size_t)k0 * D4 + t];
    const float4 ak0 = a4[(size_t)k0 * D4 + t];
    const float4 vk1 = v4[(size_t)k1 * D4 + t];
    const float4 ak1 = a4[(size_t)k1 * D4 + t];

    if (k0 >= SNUM) {
        // load cluster: rows k0+2..k0+6, both matrices, into registers
        float4 ar[5], vr[5];
        #pragma unroll
        for (int r = 0; r < 5; ++r) {
            int row = k0 + 2 + r;
            if (row >= B) row -= B;
            ar[r] = a4[(size_t)row * D4 + t];
            vr[r] = v4[(size_t)row * D4 + t];
        }
        __builtin_amdgcn_sched_barrier(0);

        acc0[0] = sq4(vk0, ak0);
        acc1[0] = sq4(vk1, ak1);
        acc0[1] = sq4(vk0, ak1);        // k0's m=0 negative row is k1
        acc0[6] = sq4(ak0, vk1);
        #pragma unroll
        for (int r = 0; r < 4; ++r) {   // k0: rows k0+2..k0+5 (m=1..4)
            acc0[2 + r] = sq4(vk0, ar[r]);
            acc0[7 + r] = sq4(ak0, vr[r]);
        }
        #pragma unroll
        for (int r = 0; r < 5; ++r) {   // k1: rows k0+2..k0+6 (m=0..4)
            acc1[1 + r] = sq4(vk1, ar[r]);
            acc1[6 + r] = sq4(ak1, vr[r]);
        }
    } else {
        // generic path (k0 < SNUM: reference's m==k duplicate) — 3 blocks only.
        acc0[0] = sq4(vk0, ak0);
        acc1[0] = sq4(vk1, ak1);
        #pragma unroll
        for (int m = 0; m < SNUM; ++m) {
            int t0 = k0 + m + 1; if (m == k0) t0 = k0 + 1; if (t0 >= B) t0 -= B;
            int t1 = k1 + m + 1; if (m == k1) t1 = k1 + 1; if (t1 >= B) t1 -= B;
            const float4 a0 = a4[(size_t)t0 * D4 + t];
            const float4 v0 = v4[(size_t)t0 * D4 + t];
            const float4 a1 = a4[(size_t)t1 * D4 + t];
            const float4 v1 = v4[(size_t)t1 * D4 + t];
            acc0[1 + m] = sq4(vk0, a0);
            acc0[6 + m] = sq4(ak0, v0);
            acc1[1 + m] = sq4(vk1, a1);
            acc1[6 + m] = sq4(ak1, v1);
        }
    }

    const float u0 = butterfly12(acc0, lane);
    const float u1 = butterfly12(acc1, lane);

    // lane -> acc id, one canonical representative lane per id
    const int b5 = (lane >> 5) & 1, b4 = (lane >> 4) & 1;
    const int b3 = (lane >> 3) & 1, b2 = (lane >> 2) & 1;
    const int id = b2 ? (8 + 2 * b4 + b5) : (4 * b3 + 2 * b4 + b5);
    const bool rep = ((lane & 3) == 0) && (!b2 || !b3);

    __shared__ float sh[4][24];
    if (rep) {
        sh[wave][id]      = u0;
        sh[wave][12 + id] = u1;
    }
    __syncthreads();

    if (t == 0) {
        float tot[22];
        #pragma unroll
        for (int i = 0; i < 11; ++i) {
            tot[i]      = sh[0][i] + sh[1][i] + sh[2][i] + sh[3][i];
            tot[11 + i] = sh[0][12 + i] + sh[1][12 + i] + sh[2][12 + i] + sh[3][12 + i];
        }
        const float dp0 = sqrtf(tot[0]);
        float dn1_0 = sqrtf(tot[1]), dn2_0 = sqrtf(tot[6]);
        const float dp1 = sqrtf(tot[11]);
        float dn1_1 = sqrtf(tot[12]), dn2_1 = sqrtf(tot[17]);
        #pragma unroll
        for (int m = 1; m < SNUM; ++m) {
            dn1_0 = fminf(dn1_0, sqrtf(tot[1 + m]));
            dn2_0 = fminf(dn2_0, sqrtf(tot[6 + m]));
            dn1_1 = fminf(dn1_1, sqrtf(tot[12 + m]));
            dn2_1 = fminf(dn2_1, sqrtf(tot[17 + m]));
        }
        const float h0 = fmaxf(MARGINL + 2.0f * dp0 - dn1_0 - dn2_0, 0.0f);
        const float h1 = fmaxf(MARGINL + 2.0f * dp1 - dn1_1 - dn2_1, 0.0f);
        bsum[blockIdx.x] = h0 + h1;
    }
}

// Deterministic single-block mean: sum n partials / B.
__global__ __launch_bounds__(1024) void mean_kernel(const float* __restrict__ bsum,
                                                    float* __restrict__ out,
                                                    int n, int B) {
    const int t = threadIdx.x;
    float s = 0.0f;
    for (int i = t; i < n; i += 1024) s += bsum[i];

    #pragma unroll
    for (int off = 32; off > 0; off >>= 1)
        s += __shfl_xor(s, off, 64);

    __shared__ float red[16];
    if ((t & 63) == 0) red[t >> 6] = s;
    __syncthreads();
    if (t == 0) {
        float tot = 0.0f;
        #pragma unroll
        for (int w = 0; w < 16; ++w) tot += red[w];
        out[0] = tot / (float)B;
    }
}

extern "C" void kernel_launch(void* const* d_in, const int* in_sizes, int n_in,
                              void* d_out, int out_size, void* d_ws, size_t ws_size,
                              hipStream_t stream) {
    const float* vfeat = (const float*)d_in[0];
    const float* afeat = (const float*)d_in[1];
    const int B = in_sizes[0] / DIM;
    const int nblocks = B / 2;

    float* bsum = (float*)d_ws;   // nblocks floats of scratch
    float* out  = (float*)d_out;

    hinge_kernel<<<nblocks, 256, 0, stream>>>(vfeat, afeat, bsum, B, nblocks);
    mean_kernel<<<1, 1024, 0, stream>>>(bsum, out, nblocks, B);
}